// Round 3
// baseline (19529.152 us; speedup 1.0000x reference)
//
#include <hip/hip_runtime.h>
#include <hip/hip_fp16.h>

// LangVisNet on MI355X. Round 3: 3-layer pipelined mRNN in ONE persistent
// kernel (378 co-resident blocks), fp16-packed register weights, write-once
// tagged h tables (no overwrite hazard, no fences), pre0 extras precomputed.
//
// pre0[s=(hw,t), g] = A2T[hw][g] + B2[t][g] + p[t,hw]*w2[g]  (validated R1/R2)

#define DEVI __device__ __forceinline__

DEVI float sigm(float x){ return 1.f/(1.f+expf(-x)); }

// ---- small kernels (validated) ----
__global__ void k_emb(const int* __restrict__ lang, const float* __restrict__ emb,
                      float* __restrict__ le){
  int t = blockIdx.x;
  size_t row = (size_t)lang[t]*1000;
  for (int e = threadIdx.x; e < 1000; e += 256)
    le[t*1000+e] = emb[row+e];
}

__global__ void k_concat(const float* __restrict__ le, const float* __restrict__ lo,
                         float* __restrict__ xc){
  int t = blockIdx.x;
  for (int j = threadIdx.x; j < 2000; j += 256)
    xc[t*2000+j] = (j < 1000) ? le[t*1000+j] : lo[t*1000 + (j-1000)];
}

__global__ void k_wl(const float* __restrict__ ccW, float* __restrict__ row8){
  int m = blockIdx.x*256 + threadIdx.x;
  if (m < 1000) row8[m] = ccW[(size_t)m*4691 + 4690];
}

template<int T>
__global__ void k_rowdot(const float* __restrict__ X, int K,
                         const float* __restrict__ W, int wstride,
                         const float* __restrict__ b1, int b1scalar,
                         const float* __restrict__ b2,
                         int biasTmax, int act,
                         float* __restrict__ out, int ostride){
  int g = blockIdx.x;
  const float* wr = W + (size_t)g*wstride;
  float acc[T];
  #pragma unroll
  for (int t=0;t<T;t++) acc[t]=0.f;
  for (int e = threadIdx.x; e < K; e += 256){
    float wv = wr[e];
    #pragma unroll
    for (int t=0;t<T;t++) acc[t] += X[(size_t)t*K+e]*wv;
  }
  __shared__ float red[T][256];
  #pragma unroll
  for (int t=0;t<T;t++) red[t][threadIdx.x]=acc[t];
  __syncthreads();
  for (int off=128; off>0; off>>=1){
    if (threadIdx.x < off){
      #pragma unroll
      for (int t=0;t<T;t++) red[t][threadIdx.x] += red[t][threadIdx.x+off];
    }
    __syncthreads();
  }
  if (threadIdx.x < T){
    float v = red[threadIdx.x][0];
    if (threadIdx.x < biasTmax){
      if (b1) v += b1scalar ? b1[0] : b1[g];
      if (b2) v += b2[g];
    }
    if (act == 1) v = sigm(v);
    out[(size_t)threadIdx.x*ostride + g] = v;
  }
}

__global__ void k_colgemm(const float* __restrict__ W, int wstride, int K,
                          const float* __restrict__ X,
                          float* __restrict__ out, int og, int ohw,
                          int G, int tail){
  __shared__ float wl[4][2688];
  int g0 = blockIdx.x*4;
  for (int i = threadIdx.x; i < 4*K; i += 256){
    int j = i / K, e = i - j*K;
    wl[j][e] = (g0+j < G) ? W[(size_t)(g0+j)*wstride + e] : 0.f;
  }
  __syncthreads();
  int hw = threadIdx.x;
  float a0=0.f,a1=0.f,a2=0.f,a3=0.f;
  #pragma unroll 4
  for (int e = 0; e < K; ++e){
    float xv = X[(size_t)e*256 + hw];
    a0 += wl[0][e]*xv; a1 += wl[1][e]*xv;
    a2 += wl[2][e]*xv; a3 += wl[3][e]*xv;
  }
  if (tail){
    float xsv = -1.f + (2.f/15.f)*(float)(hw & 15);
    float ysv = -1.f + (2.f/15.f)*(float)(hw >> 4);
    a0 += W[(size_t)(g0+0)*wstride + K]*xsv + W[(size_t)(g0+0)*wstride + K+1]*ysv;
    a1 += W[(size_t)(g0+1)*wstride + K]*xsv + W[(size_t)(g0+1)*wstride + K+1]*ysv;
    a2 += W[(size_t)(g0+2)*wstride + K]*xsv + W[(size_t)(g0+2)*wstride + K+1]*ysv;
    a3 += W[(size_t)(g0+3)*wstride + K]*xsv + W[(size_t)(g0+3)*wstride + K+1]*ysv;
  }
  float av[4] = {a0,a1,a2,a3};
  #pragma unroll
  for (int j=0;j<4;j++)
    if (g0+j < G) out[(size_t)(g0+j)*og + (size_t)hw*ohw] = av[j];
}

__global__ void k_p(const float* __restrict__ filt, const float* __restrict__ vis,
                    float* __restrict__ p){
  int hw = blockIdx.x;
  float acc[8];
  #pragma unroll
  for (int t=0;t<8;t++) acc[t]=0.f;
  for (int ch = threadIdx.x; ch < 2688; ch += 256){
    float v = vis[(size_t)ch*256 + hw];
    #pragma unroll
    for (int t=0;t<8;t++) acc[t] += filt[t*2690+ch]*v;
  }
  __shared__ float red[8][256];
  #pragma unroll
  for (int t=0;t<8;t++) red[t][threadIdx.x]=acc[t];
  __syncthreads();
  for (int off=128; off>0; off>>=1){
    if (threadIdx.x < off){
      #pragma unroll
      for (int t=0;t<8;t++) red[t][threadIdx.x]+=red[t][threadIdx.x+off];
    }
    __syncthreads();
  }
  if (threadIdx.x < 8){
    int t = threadIdx.x;
    float xsv = -1.f + (2.f/15.f)*(float)(hw & 15);
    float ysv = -1.f + (2.f/15.f)*(float)(hw >> 4);
    p[t*256+hw] = red[t][0] + filt[t*2690+2688]*xsv + filt[t*2690+2689]*ysv;
  }
}

// fp32 [4020][1005] -> fp16-pair u32 [4020][512], zero-padded cols >= 1005
__global__ void k_cvt(const float* __restrict__ src, unsigned* __restrict__ dst){
  int row = blockIdx.x;
  for (int j = threadIdx.x; j < 512; j += 256){
    int e = j*2;
    float f0 = (e   < 1005) ? src[(size_t)row*1005 + e  ] : 0.f;
    float f1 = (e+1 < 1005) ? src[(size_t)row*1005 + e+1] : 0.f;
    __half2 h2 = __floats2half2_rn(f0, f1);
    dst[(size_t)row*512 + j] = *reinterpret_cast<unsigned*>(&h2);
  }
}

// pre0[s][u][4] = A2T[hw][q*1005+u] + B2w[t][..] + p[t,hw]*B2w[8][..]
__global__ void k_pre0(const float* __restrict__ A2T, const float* __restrict__ B2w,
                       const float* __restrict__ pv, float* __restrict__ pre0){
  int s = blockIdx.x; int hw = s >> 3, t = s & 7;
  float pval = pv[t*256 + hw];
  for (int u = threadIdx.x; u < 1005; u += 512){
    float4 o;
    o.x = A2T[hw*4020 + 0*1005+u] + B2w[t*4020 + 0*1005+u] + pval*B2w[8*4020 + 0*1005+u];
    o.y = A2T[hw*4020 + 1*1005+u] + B2w[t*4020 + 1*1005+u] + pval*B2w[8*4020 + 1*1005+u];
    o.z = A2T[hw*4020 + 2*1005+u] + B2w[t*4020 + 2*1005+u] + pval*B2w[8*4020 + 2*1005+u];
    o.w = A2T[hw*4020 + 3*1005+u] + B2w[t*4020 + 3*1005+u] + pval*B2w[8*4020 + 3*1005+u];
    *reinterpret_cast<float4*>(&pre0[((size_t)s*1005 + u)*4]) = o;
  }
}

// ---- lang LSTM scan (fp32, parity handshake; S=8, validated R2) ----
__global__ __launch_bounds__(512, 2) void k_scan_lang(
    const float* __restrict__ Whh, const float* __restrict__ pre,
    float* __restrict__ hseq, unsigned long long* __restrict__ hctag, int S)
{
  constexpr int H = 1000;
  __shared__ float hx[1024];
  const int tid = threadIdx.x, w = tid >> 6, lane = tid & 63;
  const int u = blockIdx.x*8 + w;
  const int uu = (u < H) ? u : H-1;

  float wreg[4][16];
  #pragma unroll
  for (int r = 0; r < 4; ++r){
    const float* row = Whh + (size_t)(r*H + uu)*H;
    #pragma unroll
    for (int j2 = 0; j2 < 4; ++j2)
      #pragma unroll
      for (int jj = 0; jj < 4; ++jj){
        const int e = (lane<<2) + jj + (j2<<8);
        wreg[r][j2*4+jj] = (u < H && e < H) ? row[e] : 0.f;
      }
  }
  for (int i = tid; i < 1024; i += 512) if (i >= H) hx[i] = 0.f;

  float cst = 0.f;
  for (int s = 0; s < S; ++s){
    unsigned long long* src = hctag + (((unsigned)(s+1) & 1u) << 10);
    for (int i = tid; i < H; i += 512){
      unsigned long long v =
        __hip_atomic_load(&src[i], __ATOMIC_RELAXED, __HIP_MEMORY_SCOPE_AGENT);
      int it = 0;
      while ((unsigned)(v >> 32) < (unsigned)s){
        __builtin_amdgcn_s_sleep(1); ++it;
        v = (it < 16384)
          ? __hip_atomic_load(&src[i], __ATOMIC_RELAXED, __HIP_MEMORY_SCOPE_AGENT)
          : __hip_atomic_load(&src[i], __ATOMIC_ACQUIRE, __HIP_MEMORY_SCOPE_AGENT);
      }
      hx[i] = __uint_as_float((unsigned)v);
    }
    __syncthreads();

    const size_t base = (size_t)s*4*H + uu;
    float e0 = pre[base+0*(size_t)H], e1 = pre[base+1*(size_t)H];
    float e2 = pre[base+2*(size_t)H], e3 = pre[base+3*(size_t)H];

    float a0=0.f,a1=0.f,a2=0.f,a3=0.f;
    #pragma unroll
    for (int j2 = 0; j2 < 4; ++j2){
      const float4 hv = *reinterpret_cast<const float4*>(&hx[(lane<<2)+(j2<<8)]);
      a0 += wreg[0][j2*4+0]*hv.x + wreg[0][j2*4+1]*hv.y + wreg[0][j2*4+2]*hv.z + wreg[0][j2*4+3]*hv.w;
      a1 += wreg[1][j2*4+0]*hv.x + wreg[1][j2*4+1]*hv.y + wreg[1][j2*4+2]*hv.z + wreg[1][j2*4+3]*hv.w;
      a2 += wreg[2][j2*4+0]*hv.x + wreg[2][j2*4+1]*hv.y + wreg[2][j2*4+2]*hv.z + wreg[2][j2*4+3]*hv.w;
      a3 += wreg[3][j2*4+0]*hv.x + wreg[3][j2*4+1]*hv.y + wreg[3][j2*4+2]*hv.z + wreg[3][j2*4+3]*hv.w;
    }
    #pragma unroll
    for (int d = 1; d < 64; d <<= 1){
      a0 += __shfl_xor(a0,d,64); a1 += __shfl_xor(a1,d,64);
      a2 += __shfl_xor(a2,d,64); a3 += __shfl_xor(a3,d,64);
    }
    const float iv = sigm(a0+e0), fv = sigm(a1+e1);
    const float gv = tanhf(a2+e2), ov = sigm(a3+e3);
    cst = fv*cst + iv*gv;
    const float hv = ov*tanhf(cst);
    if (lane == 0 && u < H){
      const unsigned long long pk =
        ((unsigned long long)(unsigned)(s+1) << 32) | (unsigned)__float_as_uint(hv);
      __hip_atomic_store(&hctag[((unsigned)s & 1u)*1024 + u], pk,
                         __ATOMIC_RELAXED, __HIP_MEMORY_SCOPE_AGENT);
      hseq[(size_t)s*H + u] = hv;
    }
    __syncthreads();
  }
}

// ---- pipelined 3-layer mRNN ----
// 378 blocks x 512thr; layer = bid/126. Unit u = (bid%126)*8 + wave.
// h published to write-once tagged tables tg[layer][s][1024] (u64 {s+1,f32}).
DEVI unsigned long long tload(const unsigned long long* p, int acq){
  return acq ? __hip_atomic_load(p, __ATOMIC_ACQUIRE, __HIP_MEMORY_SCOPE_AGENT)
             : __hip_atomic_load(p, __ATOMIC_RELAXED, __HIP_MEMORY_SCOPE_AGENT);
}

DEVI void stage2(const unsigned long long* __restrict__ src, float* __restrict__ dst){
  const int tid = threadIdx.x;
  const int i1 = tid + 512;
  unsigned long long v0 = tload(src + tid, 0);
  const bool need1 = (i1 < 1005);
  unsigned long long v1 = need1 ? tload(src + i1, 0) : ~0ull;
  int it = 0;
  while (!(unsigned)(v0 >> 32)){
    __builtin_amdgcn_s_sleep(1); ++it;
    v0 = tload(src + tid, it >= 16384);
  }
  while (!(unsigned)(v1 >> 32)){
    __builtin_amdgcn_s_sleep(1); ++it;
    v1 = tload(src + i1, it >= 16384);
  }
  dst[tid] = __uint_as_float((unsigned)v0);
  if (need1) dst[i1] = __uint_as_float((unsigned)v1);
}

__global__ __launch_bounds__(512, 4) void k_mrnn(
    const unsigned* __restrict__ Wh0, const unsigned* __restrict__ Wh1,
    const unsigned* __restrict__ Wx1, const unsigned* __restrict__ Wh2,
    const unsigned* __restrict__ Wx2,
    const float* __restrict__ pre0,
    const float* __restrict__ mbih, const float* __restrict__ mbhh,
    unsigned long long* __restrict__ tg0,
    unsigned long long* __restrict__ tg1,
    unsigned long long* __restrict__ tg2,
    float* __restrict__ h2s)
{
  const int tid = threadIdx.x, w = tid >> 6, lane = tid & 63;
  const int bid = blockIdx.x;
  const int layer = bid / 126;
  const int lb = bid - layer*126;
  const int u = lb*8 + w;
  const int uu = (u < 1005) ? u : 1004;

  __shared__ float hx[1024];
  __shared__ float xx[1024];

  const unsigned* Wh = (layer == 0) ? Wh0 : ((layer == 1) ? Wh1 : Wh2);
  const unsigned* Wx = (layer == 1) ? Wx1 : Wx2;
  unsigned long long* tgIn  = (layer == 1) ? tg0 : tg1;
  unsigned long long* tgOwn = (layer == 0) ? tg0 : ((layer == 1) ? tg1 : tg2);

  // fp16-pair weights into registers
  unsigned wh[4][8], wxr[4][8];
  #pragma unroll
  for (int q = 0; q < 4; ++q){
    const uint2* prow = reinterpret_cast<const uint2*>(&Wh[(size_t)(q*1005 + uu)*512]);
    #pragma unroll
    for (int j2 = 0; j2 < 4; ++j2){
      uint2 v = prow[lane + j2*64];
      wh[q][j2*2] = v.x; wh[q][j2*2+1] = v.y;
    }
  }
  if (layer > 0){
    #pragma unroll
    for (int q = 0; q < 4; ++q){
      const uint2* prow = reinterpret_cast<const uint2*>(&Wx[(size_t)(q*1005 + uu)*512]);
      #pragma unroll
      for (int j2 = 0; j2 < 4; ++j2){
        uint2 v = prow[lane + j2*64];
        wxr[q][j2*2] = v.x; wxr[q][j2*2+1] = v.y;
      }
    }
  }

  float bs0=0.f, bs1=0.f, bs2=0.f, bs3=0.f;
  if (layer > 0){
    const size_t bb = (size_t)layer*4020;
    bs0 = mbih[bb + 0*1005 + uu] + mbhh[bb + 0*1005 + uu];
    bs1 = mbih[bb + 1*1005 + uu] + mbhh[bb + 1*1005 + uu];
    bs2 = mbih[bb + 2*1005 + uu] + mbhh[bb + 2*1005 + uu];
    bs3 = mbih[bb + 3*1005 + uu] + mbhh[bb + 3*1005 + uu];
  }

  for (int i = tid; i < 1024; i += 512){
    if (i >= 1005){ hx[i] = 0.f; xx[i] = 0.f; }
  }

  float cst = 0.f;
  for (int s = 0; s < 2048; ++s){
    // layer0 extras: independent of handshake -> issue first
    float e0, e1, e2, e3;
    if (layer == 0){
      const float4 pe = *reinterpret_cast<const float4*>(&pre0[((size_t)s*1005 + uu)*4]);
      e0 = pe.x; e1 = pe.y; e2 = pe.z; e3 = pe.w;
    } else { e0 = bs0; e1 = bs1; e2 = bs2; e3 = bs3; }

    if (s == 0){
      for (int i = tid; i < 1005; i += 512) hx[i] = 0.f;
    } else {
      stage2(tgOwn + (size_t)(s-1)*1024, hx);
    }
    if (layer > 0) stage2(tgIn + (size_t)s*1024, xx);
    __syncthreads();

    float acc[4] = {0.f, 0.f, 0.f, 0.f};
    #pragma unroll
    for (int j2 = 0; j2 < 4; ++j2){
      const float4 hv = *reinterpret_cast<const float4*>(&hx[(lane<<2)+(j2<<8)]);
      #pragma unroll
      for (int q = 0; q < 4; ++q){
        const float2 w0 = __half22float2(*reinterpret_cast<const __half2*>(&wh[q][j2*2]));
        const float2 w1 = __half22float2(*reinterpret_cast<const __half2*>(&wh[q][j2*2+1]));
        acc[q] += w0.x*hv.x + w0.y*hv.y + w1.x*hv.z + w1.y*hv.w;
      }
      if (layer > 0){
        const float4 xv = *reinterpret_cast<const float4*>(&xx[(lane<<2)+(j2<<8)]);
        #pragma unroll
        for (int q = 0; q < 4; ++q){
          const float2 w0 = __half22float2(*reinterpret_cast<const __half2*>(&wxr[q][j2*2]));
          const float2 w1 = __half22float2(*reinterpret_cast<const __half2*>(&wxr[q][j2*2+1]));
          acc[q] += w0.x*xv.x + w0.y*xv.y + w1.x*xv.z + w1.y*xv.w;
        }
      }
    }
    #pragma unroll
    for (int d = 1; d < 64; d <<= 1){
      acc[0] += __shfl_xor(acc[0],d,64); acc[1] += __shfl_xor(acc[1],d,64);
      acc[2] += __shfl_xor(acc[2],d,64); acc[3] += __shfl_xor(acc[3],d,64);
    }

    const float iv = sigm(acc[0]+e0), fv = sigm(acc[1]+e1);
    const float gv = tanhf(acc[2]+e2), ov = sigm(acc[3]+e3);
    cst = fv*cst + iv*gv;
    const float hv = ov*tanhf(cst);

    if (lane == 0 && u < 1005){
      const unsigned long long pk =
        ((unsigned long long)(unsigned)(s+1) << 32) | (unsigned)__float_as_uint(hv);
      __hip_atomic_store(&tgOwn[(size_t)s*1024 + u], pk,
                         __ATOMIC_RELAXED, __HIP_MEMORY_SCOPE_AGENT);
      if (layer == 2) h2s[(size_t)s*1005 + u] = hv;
    }
    __syncthreads();
  }
}

extern "C" void kernel_launch(void* const* d_in, const int* in_sizes, int n_in,
                              void* d_out, int out_size, void* d_ws, size_t ws_size,
                              hipStream_t stream){
  const float* vis   = (const float*)d_in[0];
  const int*   lang  = (const int*)  d_in[1];
  const float* emb   = (const float*)d_in[2];
  const float* lWih  = (const float*)d_in[3];
  const float* lWhh  = (const float*)d_in[4];
  const float* lbih  = (const float*)d_in[5];
  const float* lbhh  = (const float*)d_in[6];
  const float* mWih0 = (const float*)d_in[7];
  const float* mWihR = (const float*)d_in[8];
  const float* mWhh  = (const float*)d_in[9];
  const float* mbih  = (const float*)d_in[10];
  const float* mbhh  = (const float*)d_in[11];
  const float* afW   = (const float*)d_in[12];
  const float* afb   = (const float*)d_in[13];
  const float* ccW   = (const float*)d_in[14];
  const float* ccb   = (const float*)d_in[15];
  const float* ocW   = (const float*)d_in[16];
  const float* ocb   = (const float*)d_in[17];
  float* out = (float*)d_out;
  (void)in_sizes; (void)n_in; (void)out_size; (void)ws_size;

  char* wsb = (char*)d_ws;
  size_t off = 0;
  auto alloc = [&](size_t n)->char*{
    char* r = wsb + off; off = (off + n + 255) & ~(size_t)255; return r;
  };
  // zero region: lang parity buffers + 3 write-once tag tables
  unsigned long long* hctL = (unsigned long long*)alloc(2*2*1024*8);
  unsigned long long* tg0  = (unsigned long long*)alloc((size_t)2048*1024*8);
  unsigned long long* tg1  = (unsigned long long*)alloc((size_t)2048*1024*8);
  unsigned long long* tg2  = (unsigned long long*)alloc((size_t)2048*1024*8);
  size_t zbytes = off;
  float* le   = (float*)alloc(8*1000*4);
  float* hl0  = (float*)alloc(8*1000*4);
  float* hl1  = (float*)alloc(8*1000*4);
  float* prel = (float*)alloc(8*4000*4);
  float* filt = (float*)alloc(8*2690*4);
  float* pbuf = (float*)alloc(8*256*4);
  float* Abuf = (float*)alloc((size_t)1000*256*4);
  float* Bt9  = (float*)alloc(9*1000*4);
  float* B2w  = (float*)alloc(9*4020*4);
  float* A2T  = (float*)alloc((size_t)256*4020*4);
  float* Xcat = (float*)alloc(8*2000*4);
  float* pre0 = (float*)alloc((size_t)2048*1005*4*4);
  float* h2s  = (float*)alloc((size_t)2048*1005*4);
  unsigned* Wh0 = (unsigned*)alloc((size_t)4020*512*4);
  unsigned* Wh1 = (unsigned*)alloc((size_t)4020*512*4);
  unsigned* Wh2 = (unsigned*)alloc((size_t)4020*512*4);
  unsigned* Wx1 = (unsigned*)alloc((size_t)4020*512*4);
  unsigned* Wx2 = (unsigned*)alloc((size_t)4020*512*4);

  (void)hipMemsetAsync(d_ws, 0, zbytes, stream);

  // fp16 weight conversion (independent of lang path)
  k_cvt<<<4020,256,0,stream>>>(mWhh + (size_t)0*4020*1005, Wh0);
  k_cvt<<<4020,256,0,stream>>>(mWhh + (size_t)1*4020*1005, Wh1);
  k_cvt<<<4020,256,0,stream>>>(mWhh + (size_t)2*4020*1005, Wh2);
  k_cvt<<<4020,256,0,stream>>>(mWihR + (size_t)0*4020*1005, Wx1);
  k_cvt<<<4020,256,0,stream>>>(mWihR + (size_t)1*4020*1005, Wx2);

  // language path (fp32)
  k_emb<<<8,256,0,stream>>>(lang, emb, le);
  k_rowdot<8><<<4000,256,0,stream>>>(le, 1000, lWih, 1000, lbih, 0, lbhh, 8, 0, prel, 4000);
  k_scan_lang<<<125,512,0,stream>>>(lWhh, prel, hl0, hctL, 8);
  k_rowdot<8><<<4000,256,0,stream>>>(hl0, 1000, lWih+(size_t)4000*1000, 1000,
                                     lbih+4000, 0, lbhh+4000, 8, 0, prel, 4000);
  k_scan_lang<<<125,512,0,stream>>>(lWhh+(size_t)4000*1000, prel, hl1, hctL+2*1024, 8);
  // attention filter + p
  k_rowdot<8><<<2690,256,0,stream>>>(hl1, 1000, afW, 1000, afb, 0, nullptr, 8, 1, filt, 2690);
  k_p<<<256,256,0,stream>>>(filt, vis, pbuf);
  // cc decomposition -> pre0 table
  k_colgemm<<<250,256,0,stream>>>(ccW, 4691, 2688, vis, Abuf, 256, 1, 1000, 1);
  k_concat<<<8,256,0,stream>>>(le, hl1, Xcat);
  k_rowdot<8><<<1000,256,0,stream>>>(Xcat, 2000, ccW+2690, 4691, ccb, 0, nullptr, 8, 0, Bt9, 1000);
  k_wl<<<4,256,0,stream>>>(ccW, Bt9+8*1000);
  k_rowdot<9><<<4020,256,0,stream>>>(Bt9, 1000, mWih0, 1000, mbih, 0, mbhh, 8, 0, B2w, 4020);
  k_colgemm<<<1005,256,0,stream>>>(mWih0, 1000, 1000, Abuf, A2T, 1, 4020, 4020, 0);
  k_pre0<<<2048,512,0,stream>>>(A2T, B2w, pbuf, pre0);

  // pipelined 3-layer mRNN (378 co-resident blocks)
  k_mrnn<<<378,512,0,stream>>>(Wh0, Wh1, Wx1, Wh2, Wx2, pre0, mbih, mbhh,
                               tg0, tg1, tg2, h2s);

  // output head
  k_rowdot<1><<<256,256,0,stream>>>(ocW, 1005, h2s+(size_t)1792*1005, 1005,
                                    ocb, 1, nullptr, 1, 0, out, 256);
}

// Round 4
// 18184.924 us; speedup vs baseline: 1.0739x; 1.0739x over previous
//
#include <hip/hip_runtime.h>
#include <hip/hip_fp16.h>

// LangVisNet on MI355X. Round 4: pipelined 3-layer mRNN, atomic-traffic cut 4x:
// u32-packed {tag16|fp16 h} write-once tables + 63x1024-thread blocks/layer.
// R3 post-mortem: slot time = atomic read bytes / ~537 GB/s MALL service rate.
//
// pre0[s=(hw,t), g] = A2T[hw][g] + B2[t][g] + p[t,hw]*w2[g]  (validated R1-R3)

#define DEVI __device__ __forceinline__

DEVI float sigm(float x){ return 1.f/(1.f+expf(-x)); }

// ---- small kernels (validated) ----
__global__ void k_emb(const int* __restrict__ lang, const float* __restrict__ emb,
                      float* __restrict__ le){
  int t = blockIdx.x;
  size_t row = (size_t)lang[t]*1000;
  for (int e = threadIdx.x; e < 1000; e += 256)
    le[t*1000+e] = emb[row+e];
}

__global__ void k_concat(const float* __restrict__ le, const float* __restrict__ lo,
                         float* __restrict__ xc){
  int t = blockIdx.x;
  for (int j = threadIdx.x; j < 2000; j += 256)
    xc[t*2000+j] = (j < 1000) ? le[t*1000+j] : lo[t*1000 + (j-1000)];
}

__global__ void k_wl(const float* __restrict__ ccW, float* __restrict__ row8){
  int m = blockIdx.x*256 + threadIdx.x;
  if (m < 1000) row8[m] = ccW[(size_t)m*4691 + 4690];
}

template<int T>
__global__ void k_rowdot(const float* __restrict__ X, int K,
                         const float* __restrict__ W, int wstride,
                         const float* __restrict__ b1, int b1scalar,
                         const float* __restrict__ b2,
                         int biasTmax, int act,
                         float* __restrict__ out, int ostride){
  int g = blockIdx.x;
  const float* wr = W + (size_t)g*wstride;
  float acc[T];
  #pragma unroll
  for (int t=0;t<T;t++) acc[t]=0.f;
  for (int e = threadIdx.x; e < K; e += 256){
    float wv = wr[e];
    #pragma unroll
    for (int t=0;t<T;t++) acc[t] += X[(size_t)t*K+e]*wv;
  }
  __shared__ float red[T][256];
  #pragma unroll
  for (int t=0;t<T;t++) red[t][threadIdx.x]=acc[t];
  __syncthreads();
  for (int off=128; off>0; off>>=1){
    if (threadIdx.x < off){
      #pragma unroll
      for (int t=0;t<T;t++) red[t][threadIdx.x] += red[t][threadIdx.x+off];
    }
    __syncthreads();
  }
  if (threadIdx.x < T){
    float v = red[threadIdx.x][0];
    if (threadIdx.x < biasTmax){
      if (b1) v += b1scalar ? b1[0] : b1[g];
      if (b2) v += b2[g];
    }
    if (act == 1) v = sigm(v);
    out[(size_t)threadIdx.x*ostride + g] = v;
  }
}

__global__ void k_colgemm(const float* __restrict__ W, int wstride, int K,
                          const float* __restrict__ X,
                          float* __restrict__ out, int og, int ohw,
                          int G, int tail){
  __shared__ float wl[4][2688];
  int g0 = blockIdx.x*4;
  for (int i = threadIdx.x; i < 4*K; i += 256){
    int j = i / K, e = i - j*K;
    wl[j][e] = (g0+j < G) ? W[(size_t)(g0+j)*wstride + e] : 0.f;
  }
  __syncthreads();
  int hw = threadIdx.x;
  float a0=0.f,a1=0.f,a2=0.f,a3=0.f;
  #pragma unroll 4
  for (int e = 0; e < K; ++e){
    float xv = X[(size_t)e*256 + hw];
    a0 += wl[0][e]*xv; a1 += wl[1][e]*xv;
    a2 += wl[2][e]*xv; a3 += wl[3][e]*xv;
  }
  if (tail){
    float xsv = -1.f + (2.f/15.f)*(float)(hw & 15);
    float ysv = -1.f + (2.f/15.f)*(float)(hw >> 4);
    a0 += W[(size_t)(g0+0)*wstride + K]*xsv + W[(size_t)(g0+0)*wstride + K+1]*ysv;
    a1 += W[(size_t)(g0+1)*wstride + K]*xsv + W[(size_t)(g0+1)*wstride + K+1]*ysv;
    a2 += W[(size_t)(g0+2)*wstride + K]*xsv + W[(size_t)(g0+2)*wstride + K+1]*ysv;
    a3 += W[(size_t)(g0+3)*wstride + K]*xsv + W[(size_t)(g0+3)*wstride + K+1]*ysv;
  }
  float av[4] = {a0,a1,a2,a3};
  #pragma unroll
  for (int j=0;j<4;j++)
    if (g0+j < G) out[(size_t)(g0+j)*og + (size_t)hw*ohw] = av[j];
}

__global__ void k_p(const float* __restrict__ filt, const float* __restrict__ vis,
                    float* __restrict__ p){
  int hw = blockIdx.x;
  float acc[8];
  #pragma unroll
  for (int t=0;t<8;t++) acc[t]=0.f;
  for (int ch = threadIdx.x; ch < 2688; ch += 256){
    float v = vis[(size_t)ch*256 + hw];
    #pragma unroll
    for (int t=0;t<8;t++) acc[t] += filt[t*2690+ch]*v;
  }
  __shared__ float red[8][256];
  #pragma unroll
  for (int t=0;t<8;t++) red[t][threadIdx.x]=acc[t];
  __syncthreads();
  for (int off=128; off>0; off>>=1){
    if (threadIdx.x < off){
      #pragma unroll
      for (int t=0;t<8;t++) red[t][threadIdx.x]+=red[t][threadIdx.x+off];
    }
    __syncthreads();
  }
  if (threadIdx.x < 8){
    int t = threadIdx.x;
    float xsv = -1.f + (2.f/15.f)*(float)(hw & 15);
    float ysv = -1.f + (2.f/15.f)*(float)(hw >> 4);
    p[t*256+hw] = red[t][0] + filt[t*2690+2688]*xsv + filt[t*2690+2689]*ysv;
  }
}

// fp32 [4020][1005] -> fp16-pair u32 [4020][512], zero-padded cols >= 1005
__global__ void k_cvt(const float* __restrict__ src, unsigned* __restrict__ dst){
  int row = blockIdx.x;
  for (int j = threadIdx.x; j < 512; j += 256){
    int e = j*2;
    float f0 = (e   < 1005) ? src[(size_t)row*1005 + e  ] : 0.f;
    float f1 = (e+1 < 1005) ? src[(size_t)row*1005 + e+1] : 0.f;
    __half2 h2 = __floats2half2_rn(f0, f1);
    dst[(size_t)row*512 + j] = *reinterpret_cast<unsigned*>(&h2);
  }
}

// pre0[s][u][4] = A2T[hw][q*1005+u] + B2w[t][..] + p[t,hw]*B2w[8][..]
__global__ void k_pre0(const float* __restrict__ A2T, const float* __restrict__ B2w,
                       const float* __restrict__ pv, float* __restrict__ pre0){
  int s = blockIdx.x; int hw = s >> 3, t = s & 7;
  float pval = pv[t*256 + hw];
  for (int u = threadIdx.x; u < 1005; u += 512){
    float4 o;
    o.x = A2T[hw*4020 + 0*1005+u] + B2w[t*4020 + 0*1005+u] + pval*B2w[8*4020 + 0*1005+u];
    o.y = A2T[hw*4020 + 1*1005+u] + B2w[t*4020 + 1*1005+u] + pval*B2w[8*4020 + 1*1005+u];
    o.z = A2T[hw*4020 + 2*1005+u] + B2w[t*4020 + 2*1005+u] + pval*B2w[8*4020 + 2*1005+u];
    o.w = A2T[hw*4020 + 3*1005+u] + B2w[t*4020 + 3*1005+u] + pval*B2w[8*4020 + 3*1005+u];
    *reinterpret_cast<float4*>(&pre0[((size_t)s*1005 + u)*4]) = o;
  }
}

// ---- lang LSTM scan (fp32, parity handshake; S=8, validated R2/R3) ----
__global__ __launch_bounds__(512, 2) void k_scan_lang(
    const float* __restrict__ Whh, const float* __restrict__ pre,
    float* __restrict__ hseq, unsigned long long* __restrict__ hctag, int S)
{
  constexpr int H = 1000;
  __shared__ float hx[1024];
  const int tid = threadIdx.x, w = tid >> 6, lane = tid & 63;
  const int u = blockIdx.x*8 + w;
  const int uu = (u < H) ? u : H-1;

  float wreg[4][16];
  #pragma unroll
  for (int r = 0; r < 4; ++r){
    const float* row = Whh + (size_t)(r*H + uu)*H;
    #pragma unroll
    for (int j2 = 0; j2 < 4; ++j2)
      #pragma unroll
      for (int jj = 0; jj < 4; ++jj){
        const int e = (lane<<2) + jj + (j2<<8);
        wreg[r][j2*4+jj] = (u < H && e < H) ? row[e] : 0.f;
      }
  }
  for (int i = tid; i < 1024; i += 512) if (i >= H) hx[i] = 0.f;

  float cst = 0.f;
  for (int s = 0; s < S; ++s){
    unsigned long long* src = hctag + (((unsigned)(s+1) & 1u) << 10);
    for (int i = tid; i < H; i += 512){
      unsigned long long v =
        __hip_atomic_load(&src[i], __ATOMIC_RELAXED, __HIP_MEMORY_SCOPE_AGENT);
      int it = 0;
      while ((unsigned)(v >> 32) < (unsigned)s){
        __builtin_amdgcn_s_sleep(1); ++it;
        v = (it < 16384)
          ? __hip_atomic_load(&src[i], __ATOMIC_RELAXED, __HIP_MEMORY_SCOPE_AGENT)
          : __hip_atomic_load(&src[i], __ATOMIC_ACQUIRE, __HIP_MEMORY_SCOPE_AGENT);
      }
      hx[i] = __uint_as_float((unsigned)v);
    }
    __syncthreads();

    const size_t base = (size_t)s*4*H + uu;
    float e0 = pre[base+0*(size_t)H], e1 = pre[base+1*(size_t)H];
    float e2 = pre[base+2*(size_t)H], e3 = pre[base+3*(size_t)H];

    float a0=0.f,a1=0.f,a2=0.f,a3=0.f;
    #pragma unroll
    for (int j2 = 0; j2 < 4; ++j2){
      const float4 hv = *reinterpret_cast<const float4*>(&hx[(lane<<2)+(j2<<8)]);
      a0 += wreg[0][j2*4+0]*hv.x + wreg[0][j2*4+1]*hv.y + wreg[0][j2*4+2]*hv.z + wreg[0][j2*4+3]*hv.w;
      a1 += wreg[1][j2*4+0]*hv.x + wreg[1][j2*4+1]*hv.y + wreg[1][j2*4+2]*hv.z + wreg[1][j2*4+3]*hv.w;
      a2 += wreg[2][j2*4+0]*hv.x + wreg[2][j2*4+1]*hv.y + wreg[2][j2*4+2]*hv.z + wreg[2][j2*4+3]*hv.w;
      a3 += wreg[3][j2*4+0]*hv.x + wreg[3][j2*4+1]*hv.y + wreg[3][j2*4+2]*hv.z + wreg[3][j2*4+3]*hv.w;
    }
    #pragma unroll
    for (int d = 1; d < 64; d <<= 1){
      a0 += __shfl_xor(a0,d,64); a1 += __shfl_xor(a1,d,64);
      a2 += __shfl_xor(a2,d,64); a3 += __shfl_xor(a3,d,64);
    }
    const float iv = sigm(a0+e0), fv = sigm(a1+e1);
    const float gv = tanhf(a2+e2), ov = sigm(a3+e3);
    cst = fv*cst + iv*gv;
    const float hv = ov*tanhf(cst);
    if (lane == 0 && u < H){
      const unsigned long long pk =
        ((unsigned long long)(unsigned)(s+1) << 32) | (unsigned)__float_as_uint(hv);
      __hip_atomic_store(&hctag[((unsigned)s & 1u)*1024 + u], pk,
                         __ATOMIC_RELAXED, __HIP_MEMORY_SCOPE_AGENT);
      hseq[(size_t)s*H + u] = hv;
    }
    __syncthreads();
  }
}

// ---- pipelined 3-layer mRNN, u32 {tag16|fp16} tables ----
DEVI unsigned tload32(const unsigned* p, int acq){
  return acq ? __hip_atomic_load(p, __ATOMIC_ACQUIRE, __HIP_MEMORY_SCOPE_AGENT)
             : __hip_atomic_load(p, __ATOMIC_RELAXED, __HIP_MEMORY_SCOPE_AGENT);
}

DEVI float unpack_h(unsigned v){
  __half hh;
  *reinterpret_cast<unsigned short*>(&hh) = (unsigned short)(v & 0xFFFFu);
  return __half2float(hh);
}

// 189 blocks x 1024thr; layer = bid/63, 16 units/block (wave-per-unit).
__global__ __launch_bounds__(1024, 4) void k_mrnn(
    const unsigned* __restrict__ Wh0, const unsigned* __restrict__ Wh1,
    const unsigned* __restrict__ Wx1, const unsigned* __restrict__ Wh2,
    const unsigned* __restrict__ Wx2,
    const float* __restrict__ pre0,
    const float* __restrict__ mbih, const float* __restrict__ mbhh,
    unsigned* __restrict__ tg0, unsigned* __restrict__ tg1,
    unsigned* __restrict__ tg2,
    float* __restrict__ h2s)
{
  const int tid = threadIdx.x, w = tid >> 6, lane = tid & 63;
  const int bid = blockIdx.x;
  const int layer = bid / 63;
  const int lb = bid - layer*63;
  const int u = lb*16 + w;
  const int uu = (u < 1005) ? u : 1004;

  __shared__ float hx[1024];
  __shared__ float xx[1024];

  const unsigned* Wh = (layer == 0) ? Wh0 : ((layer == 1) ? Wh1 : Wh2);
  const unsigned* Wx = (layer == 1) ? Wx1 : Wx2;
  unsigned* tgIn  = (layer == 1) ? tg0 : tg1;
  unsigned* tgOwn = (layer == 0) ? tg0 : ((layer == 1) ? tg1 : tg2);

  // fp16-pair weights into registers (4 gate-rows per wave's unit)
  unsigned wh[4][8], wxr[4][8];
  #pragma unroll
  for (int q = 0; q < 4; ++q){
    const uint2* prow = reinterpret_cast<const uint2*>(&Wh[(size_t)(q*1005 + uu)*512]);
    #pragma unroll
    for (int j2 = 0; j2 < 4; ++j2){
      uint2 v = prow[lane + j2*64];
      wh[q][j2*2] = v.x; wh[q][j2*2+1] = v.y;
    }
  }
  if (layer > 0){
    #pragma unroll
    for (int q = 0; q < 4; ++q){
      const uint2* prow = reinterpret_cast<const uint2*>(&Wx[(size_t)(q*1005 + uu)*512]);
      #pragma unroll
      for (int j2 = 0; j2 < 4; ++j2){
        uint2 v = prow[lane + j2*64];
        wxr[q][j2*2] = v.x; wxr[q][j2*2+1] = v.y;
      }
    }
  }

  float bs0=0.f, bs1=0.f, bs2=0.f, bs3=0.f;
  if (layer > 0){
    const size_t bb = (size_t)layer*4020;
    bs0 = mbih[bb + 0*1005 + uu] + mbhh[bb + 0*1005 + uu];
    bs1 = mbih[bb + 1*1005 + uu] + mbhh[bb + 1*1005 + uu];
    bs2 = mbih[bb + 2*1005 + uu] + mbhh[bb + 2*1005 + uu];
    bs3 = mbih[bb + 3*1005 + uu] + mbhh[bb + 3*1005 + uu];
  }

  if (tid >= 1005){ hx[tid] = 0.f; xx[tid] = 0.f; }

  float cst = 0.f;
  for (int s = 0; s < 2048; ++s){
    // layer0 extras independent of handshake
    float e0, e1, e2, e3;
    if (layer == 0){
      const float4 pe = *reinterpret_cast<const float4*>(&pre0[((size_t)s*1005 + uu)*4]);
      e0 = pe.x; e1 = pe.y; e2 = pe.z; e3 = pe.w;
    } else { e0 = bs0; e1 = bs1; e2 = bs2; e3 = bs3; }

    // stage h(s-1) own + h_in(s); issue both loads, then resolve
    if (tid < 1005){
      const unsigned* po = tgOwn + (size_t)(s-1)*1024 + tid;
      const unsigned* pi = tgIn  + (size_t)s*1024 + tid;
      unsigned vo = (s > 0) ? tload32(po, 0) : 0u;
      unsigned vi = (layer > 0) ? tload32(pi, 0) : 0u;
      if (s > 0){
        int it = 0;
        while ((vo >> 16) != (unsigned)s){
          __builtin_amdgcn_s_sleep(1); ++it;
          vo = tload32(po, it >= 16384);
        }
      }
      if (layer > 0){
        int it = 0;
        while ((vi >> 16) != (unsigned)(s+1)){
          __builtin_amdgcn_s_sleep(1); ++it;
          vi = tload32(pi, it >= 16384);
        }
        xx[tid] = unpack_h(vi);
      }
      hx[tid] = (s > 0) ? unpack_h(vo) : 0.f;
    }
    __syncthreads();

    float acc[4] = {0.f, 0.f, 0.f, 0.f};
    #pragma unroll
    for (int j2 = 0; j2 < 4; ++j2){
      const float4 hv = *reinterpret_cast<const float4*>(&hx[(lane<<2)+(j2<<8)]);
      #pragma unroll
      for (int q = 0; q < 4; ++q){
        const float2 w0 = __half22float2(*reinterpret_cast<const __half2*>(&wh[q][j2*2]));
        const float2 w1 = __half22float2(*reinterpret_cast<const __half2*>(&wh[q][j2*2+1]));
        acc[q] += w0.x*hv.x + w0.y*hv.y + w1.x*hv.z + w1.y*hv.w;
      }
      if (layer > 0){
        const float4 xv = *reinterpret_cast<const float4*>(&xx[(lane<<2)+(j2<<8)]);
        #pragma unroll
        for (int q = 0; q < 4; ++q){
          const float2 w0 = __half22float2(*reinterpret_cast<const __half2*>(&wxr[q][j2*2]));
          const float2 w1 = __half22float2(*reinterpret_cast<const __half2*>(&wxr[q][j2*2+1]));
          acc[q] += w0.x*xv.x + w0.y*xv.y + w1.x*xv.z + w1.y*xv.w;
        }
      }
    }
    #pragma unroll
    for (int d = 1; d < 64; d <<= 1){
      acc[0] += __shfl_xor(acc[0],d,64); acc[1] += __shfl_xor(acc[1],d,64);
      acc[2] += __shfl_xor(acc[2],d,64); acc[3] += __shfl_xor(acc[3],d,64);
    }

    const float iv = sigm(acc[0]+e0), fv = sigm(acc[1]+e1);
    const float gv = tanhf(acc[2]+e2), ov = sigm(acc[3]+e3);
    cst = fv*cst + iv*gv;
    const float hv = ov*tanhf(cst);

    if (lane == 0 && u < 1005){
      __half hh = __float2half_rn(hv);
      const unsigned pk = ((unsigned)(s+1) << 16)
                        | (unsigned)*reinterpret_cast<unsigned short*>(&hh);
      __hip_atomic_store(&tgOwn[(size_t)s*1024 + u], pk,
                         __ATOMIC_RELAXED, __HIP_MEMORY_SCOPE_AGENT);
      if (layer == 2) h2s[(size_t)s*1005 + u] = hv;
    }
    __syncthreads();
  }
}

extern "C" void kernel_launch(void* const* d_in, const int* in_sizes, int n_in,
                              void* d_out, int out_size, void* d_ws, size_t ws_size,
                              hipStream_t stream){
  const float* vis   = (const float*)d_in[0];
  const int*   lang  = (const int*)  d_in[1];
  const float* emb   = (const float*)d_in[2];
  const float* lWih  = (const float*)d_in[3];
  const float* lWhh  = (const float*)d_in[4];
  const float* lbih  = (const float*)d_in[5];
  const float* lbhh  = (const float*)d_in[6];
  const float* mWih0 = (const float*)d_in[7];
  const float* mWihR = (const float*)d_in[8];
  const float* mWhh  = (const float*)d_in[9];
  const float* mbih  = (const float*)d_in[10];
  const float* mbhh  = (const float*)d_in[11];
  const float* afW   = (const float*)d_in[12];
  const float* afb   = (const float*)d_in[13];
  const float* ccW   = (const float*)d_in[14];
  const float* ccb   = (const float*)d_in[15];
  const float* ocW   = (const float*)d_in[16];
  const float* ocb   = (const float*)d_in[17];
  float* out = (float*)d_out;
  (void)in_sizes; (void)n_in; (void)out_size; (void)ws_size;

  char* wsb = (char*)d_ws;
  size_t off = 0;
  auto alloc = [&](size_t n)->char*{
    char* r = wsb + off; off = (off + n + 255) & ~(size_t)255; return r;
  };
  // zero region: lang parity buffers (u64) + 3 write-once u32 tag tables
  unsigned long long* hctL = (unsigned long long*)alloc(2*2*1024*8);
  unsigned* tg0 = (unsigned*)alloc((size_t)2048*1024*4);
  unsigned* tg1 = (unsigned*)alloc((size_t)2048*1024*4);
  unsigned* tg2 = (unsigned*)alloc((size_t)2048*1024*4);
  size_t zbytes = off;
  float* le   = (float*)alloc(8*1000*4);
  float* hl0  = (float*)alloc(8*1000*4);
  float* hl1  = (float*)alloc(8*1000*4);
  float* prel = (float*)alloc(8*4000*4);
  float* filt = (float*)alloc(8*2690*4);
  float* pbuf = (float*)alloc(8*256*4);
  float* Abuf = (float*)alloc((size_t)1000*256*4);
  float* Bt9  = (float*)alloc(9*1000*4);
  float* B2w  = (float*)alloc(9*4020*4);
  float* A2T  = (float*)alloc((size_t)256*4020*4);
  float* Xcat = (float*)alloc(8*2000*4);
  float* pre0 = (float*)alloc((size_t)2048*1005*4*4);
  float* h2s  = (float*)alloc((size_t)2048*1005*4);
  unsigned* Wh0 = (unsigned*)alloc((size_t)4020*512*4);
  unsigned* Wh1 = (unsigned*)alloc((size_t)4020*512*4);
  unsigned* Wh2 = (unsigned*)alloc((size_t)4020*512*4);
  unsigned* Wx1 = (unsigned*)alloc((size_t)4020*512*4);
  unsigned* Wx2 = (unsigned*)alloc((size_t)4020*512*4);

  (void)hipMemsetAsync(d_ws, 0, zbytes, stream);

  // fp16 weight conversion
  k_cvt<<<4020,256,0,stream>>>(mWhh + (size_t)0*4020*1005, Wh0);
  k_cvt<<<4020,256,0,stream>>>(mWhh + (size_t)1*4020*1005, Wh1);
  k_cvt<<<4020,256,0,stream>>>(mWhh + (size_t)2*4020*1005, Wh2);
  k_cvt<<<4020,256,0,stream>>>(mWihR + (size_t)0*4020*1005, Wx1);
  k_cvt<<<4020,256,0,stream>>>(mWihR + (size_t)1*4020*1005, Wx2);

  // language path (fp32)
  k_emb<<<8,256,0,stream>>>(lang, emb, le);
  k_rowdot<8><<<4000,256,0,stream>>>(le, 1000, lWih, 1000, lbih, 0, lbhh, 8, 0, prel, 4000);
  k_scan_lang<<<125,512,0,stream>>>(lWhh, prel, hl0, hctL, 8);
  k_rowdot<8><<<4000,256,0,stream>>>(hl0, 1000, lWih+(size_t)4000*1000, 1000,
                                     lbih+4000, 0, lbhh+4000, 8, 0, prel, 4000);
  k_scan_lang<<<125,512,0,stream>>>(lWhh+(size_t)4000*1000, prel, hl1, hctL+2*1024, 8);
  // attention filter + p
  k_rowdot<8><<<2690,256,0,stream>>>(hl1, 1000, afW, 1000, afb, 0, nullptr, 8, 1, filt, 2690);
  k_p<<<256,256,0,stream>>>(filt, vis, pbuf);
  // cc decomposition -> pre0 table
  k_colgemm<<<250,256,0,stream>>>(ccW, 4691, 2688, vis, Abuf, 256, 1, 1000, 1);
  k_concat<<<8,256,0,stream>>>(le, hl1, Xcat);
  k_rowdot<8><<<1000,256,0,stream>>>(Xcat, 2000, ccW+2690, 4691, ccb, 0, nullptr, 8, 0, Bt9, 1000);
  k_wl<<<4,256,0,stream>>>(ccW, Bt9+8*1000);
  k_rowdot<9><<<4020,256,0,stream>>>(Bt9, 1000, mWih0, 1000, mbih, 0, mbhh, 8, 0, B2w, 4020);
  k_colgemm<<<1005,256,0,stream>>>(mWih0, 1000, 1000, Abuf, A2T, 1, 4020, 4020, 0);
  k_pre0<<<2048,512,0,stream>>>(A2T, B2w, pbuf, pre0);

  // pipelined 3-layer mRNN (189 co-resident 1024-thread blocks)
  k_mrnn<<<189,1024,0,stream>>>(Wh0, Wh1, Wx1, Wh2, Wx2, pre0, mbih, mbhh,
                                tg0, tg1, tg2, h2s);

  // output head
  k_rowdot<1><<<256,256,0,stream>>>(ocW, 1005, h2s+(size_t)1792*1005, 1005,
                                    ocb, 1, nullptr, 1, 0, out, 256);
}